// Round 3
// baseline (179.158 us; speedup 1.0000x reference)
//
#include <hip/hip_runtime.h>
#include <stdint.h>

// Problem constants (fixed by the reference)
#define BQ   2
#define NQ   8192
#define D1Q  128
#define D2Q  256
#define OUTQ 128
#define CATQ 384   // D1+D2
#define KQ   16

#define NBIN 4096          // 16x16x16 Morton cells
#define RED_MARGIN 1e-3f   // proxy-vs-exact bound margin (phase-1 threshold)
#define LB_MARGIN  1e-2f   // group-box lower-bound slack (covers all fp error)

// workspace byte offsets
#define WS_WFH   0          // ushort[49152]
#define WS_WFL   98304      // ushort[49152]
#define WS_HIST  196608     // u32[4][4096]
#define WS_SPXYZ 262144     // float4[2][8192] sorted points (x,y,z,npy-norm)
#define WS_QSXYZ 524288     // float4[2][8192] sorted queries (x,y,z,npy-s2)
#define WS_SPIDX 786432     // u16[2][8192] orig point idx
#define WS_QSIDX 819200     // u16[2][8192] orig query idx
#define WS_GB    851968     // u32[256][8] enc'd group AABB: lo x,y,z,_ hi x,y,z,_
// end: 860160 bytes

// bf16 split helpers (RNE)
__device__ __forceinline__ ushort f2bf(float f) {
    uint32_t u = __float_as_uint(f);
    return (ushort)((u + 0x7FFFu + ((u >> 16) & 1u)) >> 16);
}
__device__ __forceinline__ float bf2f(ushort h) {
    return __uint_as_float((uint32_t)h << 16);
}

// monotone float<->uint order map (same map as wball keys)
__device__ __forceinline__ uint32_t encf(float f) {
    uint32_t b = __float_as_uint(f);
    return b ^ (0x80000000u | (uint32_t)((int32_t)b >> 31));
}
__device__ __forceinline__ float decf(uint32_t u) {
    uint32_t bits = (u & 0x80000000u) ? (u ^ 0x80000000u) : ~u;
    return __uint_as_float(bits);
}

__device__ __forceinline__ uint32_t mbcnt64(uint64_t m) {
    return __builtin_amdgcn_mbcnt_hi((uint32_t)(m >> 32),
           __builtin_amdgcn_mbcnt_lo((uint32_t)m, 0u));
}

typedef __attribute__((ext_vector_type(8))) short short8v;   // 8 bf16 (4 VGPRs)
typedef __attribute__((ext_vector_type(4))) float f32x4v;    // MFMA accumulator

// 4-bit/dim Morton bin (any binning is CORRECT; it only affects pruning rate)
__device__ __forceinline__ int mort_bin(float x, float y, float z) {
    int bx = (int)((x + 5.0f) * 1.6f); bx = bx < 0 ? 0 : (bx > 15 ? 15 : bx);
    int by = (int)((y + 5.0f) * 1.6f); by = by < 0 ? 0 : (by > 15 ? 15 : by);
    int bz = (int)((z + 5.0f) * 1.6f); bz = bz < 0 ? 0 : (bz > 15 ? 15 : bz);
    int k = 0;
    #pragma unroll
    for (int t = 0; t < 4; ++t)
        k |= (((bx >> t) & 1) << (3 * t)) | (((by >> t) & 1) << (3 * t + 1)) |
             (((bz >> t) & 1) << (3 * t + 2));
    return k;
}

// ---------------------------------------------------------------------------
// P0: W split to bf16 hi/lo in MFMA B-fragment layout + clear hist + init AABBs
// ---------------------------------------------------------------------------
__global__ void prep_w_kernel(const float* __restrict__ W,
                              ushort* __restrict__ Wfh, ushort* __restrict__ Wfl,
                              uint32_t* __restrict__ hist,
                              uint32_t* __restrict__ gbU) {
    int flat = blockIdx.x * 256 + threadIdx.x;
    if (flat < CATQ * OUTQ) {
        int r    = flat & 7;
        int lane = (flat >> 3) & 63;
        int ctk  = flat >> 9;
        int ct   = ctk & 7;
        int kt   = ctk >> 3;
        int o = ct * 16 + (lane & 15);
        int k = kt * 32 + (lane >> 4) * 8 + r;
        float v  = W[o * CATQ + k];
        ushort h = f2bf(v);
        Wfh[flat] = h;
        Wfl[flat] = f2bf(v - bf2f(h));
    }
    if (flat < 4 * NBIN) hist[flat] = 0u;
    if (flat < 256 * 8)  gbU[flat] = ((flat & 7) >= 4) ? 0u : 0xFFFFFFFFu;
}

// ---------------------------------------------------------------------------
// P1: Morton histograms for points (xyz1) and queries (xyz2), per batch.
// ---------------------------------------------------------------------------
__global__ void hist_kernel(const float* __restrict__ xyz1,
                            const float* __restrict__ xyz2,
                            uint32_t* __restrict__ hist) {
    int i = blockIdx.x * 256 + threadIdx.x;   // 0..32767
    if (i < BQ * NQ) {
        int batch = i >> 13;
        const float* p = xyz1 + (size_t)i * 3;
        int bin = mort_bin(p[0], p[1], p[2]);
        atomicAdd(&hist[batch * NBIN + bin], 1u);
    } else {
        int j = i - BQ * NQ;
        int batch = j >> 13;
        const float* p = xyz2 + (size_t)j * 3;
        int bin = mort_bin(p[0], p[1], p[2]);
        atomicAdd(&hist[(2 + batch) * NBIN + bin], 1u);
    }
}

// ---------------------------------------------------------------------------
// P2: exclusive prefix over each of the 4 histograms (one block per array).
// ---------------------------------------------------------------------------
__global__ void prefix_kernel(uint32_t* __restrict__ hist) {
    __shared__ uint32_t sc[1024];
    uint32_t* h = hist + (size_t)blockIdx.x * NBIN;
    int t = threadIdx.x;
    uint32_t v0 = h[4 * t], v1 = h[4 * t + 1], v2 = h[4 * t + 2], v3 = h[4 * t + 3];
    uint32_t s = v0 + v1 + v2 + v3;
    sc[t] = s;
    __syncthreads();
    for (int d = 1; d < 1024; d <<= 1) {
        uint32_t x = (t >= d) ? sc[t - d] : 0u;
        __syncthreads();
        sc[t] += x;
        __syncthreads();
    }
    uint32_t excl = sc[t] - s;
    h[4 * t]     = excl;
    h[4 * t + 1] = excl + v0;
    h[4 * t + 2] = excl + v0 + v1;
    h[4 * t + 3] = excl + v0 + v1 + v2;
}

// ---------------------------------------------------------------------------
// P3: scatter into Morton order; npy-exact norm/s2; fused group-AABB atomics.
// ---------------------------------------------------------------------------
__global__ void scatter_kernel(const float* __restrict__ xyz1,
                               const float* __restrict__ xyz2,
                               uint32_t* __restrict__ hist,
                               float4* __restrict__ sp_xyzn,
                               float4* __restrict__ qs_xyzw,
                               ushort* __restrict__ sp_idx,
                               ushort* __restrict__ qs_idx,
                               uint32_t* __restrict__ gbU) {
    int i = blockIdx.x * 256 + threadIdx.x;
    if (i < BQ * NQ) {
        int batch = i >> 13;
        const float* p = xyz1 + (size_t)i * 3;
        float x = p[0], y = p[1], z = p[2];
        int bin = mort_bin(x, y, z);
        uint32_t pos = atomicAdd(&hist[batch * NBIN + bin], 1u);
        float n;
        {
            #pragma clang fp contract(off)
            float px = x * x, py = y * y, pz = z * z;
            n = (px + py) + pz;
        }
        sp_xyzn[batch * NQ + pos] = make_float4(x, y, z, n);
        sp_idx[batch * NQ + pos]  = (ushort)(i & (NQ - 1));
        // fused group AABB (group = 64 consecutive sorted slots)
        uint32_t* gw = gbU + ((size_t)batch * 128 + (pos >> 6)) * 8;
        atomicMin(&gw[0], encf(x));
        atomicMin(&gw[1], encf(y));
        atomicMin(&gw[2], encf(z));
        atomicMax(&gw[4], encf(x));
        atomicMax(&gw[5], encf(y));
        atomicMax(&gw[6], encf(z));
    } else {
        int j = i - BQ * NQ;
        int batch = j >> 13;
        const float* p = xyz2 + (size_t)j * 3;
        float x = p[0], y = p[1], z = p[2];
        int bin = mort_bin(x, y, z);
        uint32_t pos = atomicAdd(&hist[(2 + batch) * NBIN + bin], 1u);
        float s2;
        {
            #pragma clang fp contract(off)
            float px = x * x, py = y * y, pz = z * z;
            s2 = (px + py) + pz;
        }
        qs_xyzw[batch * NQ + pos] = make_float4(x, y, z, s2);
        qs_idx[batch * NQ + pos]  = (ushort)(j & (NQ - 1));
    }
}

// numpy-exact squared distance (same rounding as the reference BLAS path)
__device__ __forceinline__ float npy_d2(float4 pt, float qx, float qy, float qz,
                                        float s2) {
    #pragma clang fp contract(off)
    float d0  = pt.x * qx;                 // rounded product
    float dot = fmaf(pt.y, qy, d0);        // explicit FMA chain
    dot       = fmaf(pt.z, qz, dot);
    float tt  = s2 + pt.w;                 // rounded add
    return tt - 2.0f * dot;                // 2*dot exact; rounded sub
}

// 4-op reduced proxy: exact_d2 ~= s2 + red within ~1.5e-5. Phase-1 bound only.
__device__ __forceinline__ float red_r(float4 pt, float qx, float qy, float qz) {
    float dot = fmaf(pt.z, qz, fmaf(pt.y, qy, pt.x * qx));
    return fmaf(-2.0f, dot, pt.w);
}

// full ascending bitonic sort of one uint64 per lane across the wave
__device__ __forceinline__ uint64_t sort64(uint64_t x, int lane) {
    #pragma unroll
    for (int k = 2; k <= 64; k <<= 1) {
        #pragma unroll
        for (int j = k >> 1; j > 0; j >>= 1) {
            uint64_t p = __shfl_xor((unsigned long long)x, j, 64);
            bool keep_min = (((lane & j) == 0) == ((lane & k) == 0));
            bool pless    = p < x;
            x = (pless == keep_min) ? p : x;   // ties: same value either way
        }
    }
    return x;
}

// ---------------------------------------------------------------------------
// Fused kernel (R16): barrier-free per-wave phases.
//  vs R15 (counters: VALU 36%, MFMA 2.5%, HBM 13%, occ 28% -> latency/sync
//  bound, not throughput bound):
//  - Phases 1-2 read Morton-sorted points DIRECTLY from global (coalesced,
//    L1/L2-hit; all 4 waves touch the same lines) -> zero LDS staging, zero
//    barriers until the LDS-reuse boundary. Exactly 2 __syncthreads total.
//  - Group-AABB test is per-WAVE (4-query box + wave-max threshold): strictly
//    tighter than the block test -> fewer phase-2 groups. Validity unchanged:
//    lb <= true_d2 <= npy_d2 + eps <= that[j] + LB_MARGIN.
//  - Phase-1 window 2048 -> 1024 (rank-15-of-64-lane-minima bound is valid
//    for any 64-partition subset; Morton-local 1024 keeps it tight).
//  - wball / survivor list are strictly per-wave LDS regions (no sharing).
//  Selection + stages 2-3 bit-identical to R15.
// ---------------------------------------------------------------------------
__global__ __launch_bounds__(256, 4) void fused_kernel(
        const float4* __restrict__ sp_xyzn, const ushort* __restrict__ sp_idx,
        const float4* __restrict__ qs_xyzw, const ushort* __restrict__ qs_idx,
        const float* __restrict__ points1, const float* __restrict__ points2,
        const ushort* __restrict__ Wfh, const ushort* __restrict__ Wfl,
        const float* __restrict__ bias, const uint32_t* __restrict__ gbU,
        float* __restrict__ out) {
    __shared__ __align__(16) char smem[26368];
    uint64_t* wball = (uint64_t*)smem;               // [0,16K) per-wave rows
    ushort*   cat_h = (ushort*)smem;                 // [0,12544)   stages 2-3
    ushort*   cat_l = (ushort*)(smem + 12544);       // [12544,25088)
    ushort*   slist = (ushort*)(smem + 25088);       // [25088,26112) [4][128]
    ushort*   qsl   = (ushort*)(smem + 26112);       // [16] orig query idx

    const int tid   = threadIdx.x;
    const int lane  = tid & 63;
    const int w     = tid >> 6;
    const int blk   = blockIdx.x;
    const int b     = blk >> 9;                     // batch
    const int qslot = (blk & 511) * 16;             // sorted-query base

    if (tid < 16) qsl[tid] = qs_idx[b * NQ + qslot + tid];

    // wave's 4 sorted queries (s2 precomputed npy-exact)
    float qx[4], qy[4], qz[4], s2[4];
    int   oqi[4];
    #pragma unroll
    for (int j = 0; j < 4; ++j) {
        float4 q = qs_xyzw[(size_t)b * NQ + qslot + w * 4 + j];
        qx[j] = q.x; qy[j] = q.y; qz[j] = q.z; s2[j] = q.w;
        oqi[j] = (int)qs_idx[b * NQ + qslot + w * 4 + j];
    }

    const float4* spb = sp_xyzn + (size_t)b * NQ;
    const ushort* spi = sp_idx  + (size_t)b * NQ;

    // ------- Phase 1: proxy lane-min over a 1024-pt window (global direct) ----
    int wstart = qslot + 8 - 512;
    if (wstart < 0) wstart = 0;
    if (wstart > NQ - 1024) wstart = NQ - 1024;
    wstart &= ~63;
    const float4* win = spb + wstart;

    float mn[4];
    #pragma unroll
    for (int j = 0; j < 4; ++j) mn[j] = __uint_as_float(0x7F800000u);

    #pragma unroll 4
    for (int s = 0; s < 16; ++s) {
        float4 pt = win[s * 64 + lane];
        #pragma unroll
        for (int j = 0; j < 4; ++j)
            mn[j] = fminf(mn[j], red_r(pt, qx[j], qy[j], qz[j]));
    }

    // 4 float bitonic sorts of lane minima; that[j] = s2 + rank15 + margin
    float that[4];
    #pragma unroll
    for (int j = 0; j < 4; ++j) {
        float x = mn[j];
        #pragma unroll
        for (int k = 2; k <= 64; k <<= 1) {
            #pragma unroll
            for (int jj = k >> 1; jj > 0; jj >>= 1) {
                float px = __shfl_xor(x, jj, 64);
                bool keep_min = (((lane & jj) == 0) == ((lane & k) == 0));
                float mnv = fminf(x, px), mxv = fmaxf(x, px);
                x = keep_min ? mnv : mxv;
            }
        }
        that[j] = s2[j] + __shfl(x, 15, 64) + RED_MARGIN;
    }

    // ------- per-WAVE group-box test (uniform math; ballot compaction) -------
    ushort* sl = slist + w * 128;
    int scnt_w = 0;
    {
        // wave query box + wave-max threshold (uniform across lanes)
        float qlx = fminf(fminf(qx[0], qx[1]), fminf(qx[2], qx[3]));
        float qly = fminf(fminf(qy[0], qy[1]), fminf(qy[2], qy[3]));
        float qlz = fminf(fminf(qz[0], qz[1]), fminf(qz[2], qz[3]));
        float qhx = fmaxf(fmaxf(qx[0], qx[1]), fmaxf(qx[2], qx[3]));
        float qhy = fmaxf(fmaxf(qy[0], qy[1]), fmaxf(qy[2], qy[3]));
        float qhz = fmaxf(fmaxf(qz[0], qz[1]), fmaxf(qz[2], qz[3]));
        float tmax = fmaxf(fmaxf(that[0], that[1]), fmaxf(that[2], that[3]))
                   + LB_MARGIN;
        #pragma unroll
        for (int h = 0; h < 2; ++h) {
            int g = h * 64 + lane;
            const uint32_t* gw = gbU + ((size_t)b * 128 + g) * 8;
            float glx = decf(gw[0]), gly = decf(gw[1]), glz = decf(gw[2]);
            float ghx = decf(gw[4]), ghy = decf(gw[5]), ghz = decf(gw[6]);
            float dx = fmaxf(fmaxf(qlx - ghx, glx - qhx), 0.f);
            float dy = fmaxf(fmaxf(qly - ghy, gly - qhy), 0.f);
            float dz = fmaxf(fmaxf(qlz - ghz, glz - qhz), 0.f);
            float lb = dx * dx;
            lb = fmaf(dy, dy, lb);
            lb = fmaf(dz, dz, lb);
            bool sv = (lb <= tmax);
            uint64_t m = __ballot((int)sv);
            if (sv) sl[scnt_w + mbcnt64(m)] = (ushort)g;
            scnt_w += (int)__popcll(m);
        }
    }

    // ------- Phase 2: exact scan of wave's surviving groups (global direct) ---
    uint32_t cnt[4] = {0u, 0u, 0u, 0u};
    for (int i = 0; i < scnt_w; ++i) {
        const int g = (int)sl[i];                 // uniform LDS broadcast
        float4   pt   = spb[g * 64 + lane];       // coalesced, L1/L2-hit
        uint32_t pidx = (uint32_t)spi[g * 64 + lane];
        #pragma unroll
        for (int j = 0; j < 4; ++j) {
            float d2 = npy_d2(pt, qx[j], qy[j], qz[j], s2[j]);
            bool  v  = (d2 <= that[j]);
            uint64_t mask = __ballot((int)v);
            if (mask != 0ull) {                   // scalar gate
                if (v) {
                    uint32_t pos    = cnt[j] + mbcnt64(mask);
                    uint32_t bits   = __float_as_uint(d2);
                    uint32_t mapped = bits ^ (0x80000000u |
                                      (uint32_t)((int32_t)bits >> 31));
                    if (pos < 128u)
                        wball[(w * 4 + j) * 128 + pos] =
                            ((uint64_t)mapped << 32) | (uint64_t)pidx;
                }
                cnt[j] += (uint32_t)__popcll(mask);
            }
        }
    }

    // ---------------- per-query selection + weights (unchanged) ----------------
    int   myidxA[4];
    float mywgtA[4];
    #pragma unroll
    for (int j = 0; j < 4; ++j) {
        const uint64_t* wb = wball + (size_t)(w * 4 + j) * 128;
        const uint32_t c = cnt[j];
        uint64_t mykey;
        if (c <= 64u) {                            // normal path
            uint64_t k0 = (lane < (int)c) ? wb[lane] : ~0ull;
            mykey = sort64(k0, lane);
        } else {                                   // uniform fallback
            uint32_t cc = c > 128u ? 128u : c;
            uint64_t k0 = wb[lane];
            uint64_t k1 = (lane + 64 < (int)cc) ? wb[lane + 64] : ~0ull;
            k0 = sort64(k0, lane);
            k1 = sort64(k1, lane);
            uint64_t t1 = __shfl((unsigned long long)k1, lane & 15, 64);
            uint64_t km = (lane < 16) ? k0 : ((lane < 32) ? t1 : ~0ull);
            mykey = sort64(km, lane);
        }
        uint32_t mhi   = (uint32_t)(mykey >> 32);
        uint32_t rbits = (mhi & 0x80000000u) ? (mhi ^ 0x80000000u) : ~mhi;
        float    d2w   = __uint_as_float(rbits);
        myidxA[j] = (int)(uint32_t)(mykey & 0xFFFFFFFFull);
        float recip = (lane < KQ) ? (1.0f / (d2w + 1e-8f)) : 0.0f;
        float tot = recip;
        #pragma unroll
        for (int sh = 1; sh < 16; sh <<= 1) tot += __shfl_xor(tot, sh, 64);
        mywgtA[j] = recip / tot;                   // valid in lanes 0..15
    }

    // LDS reuse boundary: all waves done reading wball before cat overwrites it
    __syncthreads();

    // ------- Stage 2: build cat (bf16 hi/lo split) [16][392] in LDS -------
    const float* p2b = points2 + (size_t)b * NQ * D2Q;
    #pragma unroll
    for (int j = 0; j < 4; ++j) {
        const int qi = w * 4 + j;
        // p1 part: 128 floats, lanes 0..31 (orig query row via permutation)
        if (lane < 32) {
            float4 p = ((const float4*)(points1 +
                        (size_t)(b * NQ + oqi[j]) * D1Q))[lane];
            ushort4 hv, lv;
            hv.x = f2bf(p.x); lv.x = f2bf(p.x - bf2f(hv.x));
            hv.y = f2bf(p.y); lv.y = f2bf(p.y - bf2f(hv.y));
            hv.z = f2bf(p.z); lv.z = f2bf(p.z - bf2f(hv.z));
            hv.w = f2bf(p.w); lv.w = f2bf(p.w - bf2f(hv.w));
            *(ushort4*)&cat_h[qi * 392 + lane * 4] = hv;
            *(ushort4*)&cat_l[qi * 392 + lane * 4] = lv;
        }
        // interp part: 256 floats, all 64 lanes; k ascending (reference order)
        float4 acc = make_float4(0.f, 0.f, 0.f, 0.f);
        #pragma unroll
        for (int k = 0; k < KQ; ++k) {
            int   kk = __builtin_amdgcn_readlane(myidxA[j], k);
            float wk = __uint_as_float((uint32_t)__builtin_amdgcn_readlane(
                           (int)__float_as_uint(mywgtA[j]), k));
            float4 row = ((const float4*)(p2b + (size_t)kk * D2Q))[lane];
            acc.x = fmaf(wk, row.x, acc.x);
            acc.y = fmaf(wk, row.y, acc.y);
            acc.z = fmaf(wk, row.z, acc.z);
            acc.w = fmaf(wk, row.w, acc.w);
        }
        {
            ushort4 hv, lv;
            hv.x = f2bf(acc.x); lv.x = f2bf(acc.x - bf2f(hv.x));
            hv.y = f2bf(acc.y); lv.y = f2bf(acc.y - bf2f(hv.y));
            hv.z = f2bf(acc.z); lv.z = f2bf(acc.z - bf2f(hv.z));
            hv.w = f2bf(acc.w); lv.w = f2bf(acc.w - bf2f(hv.w));
            *(ushort4*)&cat_h[qi * 392 + D1Q + lane * 4] = hv;
            *(ushort4*)&cat_l[qi * 392 + D1Q + lane * 4] = lv;
        }
    }
    __syncthreads();

    // ------- Stage 3: MFMA GEMM  C[16][128] = cat[16][384] @ Wt[384][128] -------
    {
        const int arow = lane & 15;
        const int koff = (lane >> 4) * 8;
        const int ct0  = w * 2;
        f32x4v acc0 = {0.f, 0.f, 0.f, 0.f};
        f32x4v acc1 = {0.f, 0.f, 0.f, 0.f};
        #pragma unroll 4
        for (int kt = 0; kt < 12; ++kt) {
            short8v ah = *(const short8v*)&cat_h[arow * 392 + kt * 32 + koff];
            short8v al = *(const short8v*)&cat_l[arow * 392 + kt * 32 + koff];
            const ushort* bhp = Wfh + ((size_t)(kt * 8 + ct0) * 64 + lane) * 8;
            const ushort* blp = Wfl + ((size_t)(kt * 8 + ct0) * 64 + lane) * 8;
            short8v bh0 = *(const short8v*)bhp;
            short8v bl0 = *(const short8v*)blp;
            short8v bh1 = *(const short8v*)(bhp + 512);
            short8v bl1 = *(const short8v*)(blp + 512);
            acc0 = __builtin_amdgcn_mfma_f32_16x16x32_bf16(ah, bh0, acc0, 0, 0, 0);
            acc0 = __builtin_amdgcn_mfma_f32_16x16x32_bf16(al, bh0, acc0, 0, 0, 0);
            acc0 = __builtin_amdgcn_mfma_f32_16x16x32_bf16(ah, bl0, acc0, 0, 0, 0);
            acc1 = __builtin_amdgcn_mfma_f32_16x16x32_bf16(ah, bh1, acc1, 0, 0, 0);
            acc1 = __builtin_amdgcn_mfma_f32_16x16x32_bf16(al, bh1, acc1, 0, 0, 0);
            acc1 = __builtin_amdgcn_mfma_f32_16x16x32_bf16(ah, bl1, acc1, 0, 0, 0);
        }
        // C/D layout: col = lane&15, row = (lane>>4)*4 + r (m89-verified);
        // rows scatter through the query permutation.
        const int col0   = ct0 * 16 + (lane & 15);
        const int r0slot = (lane >> 4) * 4;
        const float bv0 = bias[col0];
        const float bv1 = bias[col0 + 16];
        #pragma unroll
        for (int r = 0; r < 4; ++r) {
            int oq = (int)qsl[r0slot + r];
            size_t rowoff = (size_t)(b * NQ + oq) * OUTQ;
            out[rowoff + col0]      = acc0[r] + bv0;
            out[rowoff + col0 + 16] = acc1[r] + bv1;
        }
    }
}

// ---------------------------------------------------------------------------
// Launch
// ---------------------------------------------------------------------------
extern "C" void kernel_launch(void* const* d_in, const int* in_sizes, int n_in,
                              void* d_out, int out_size, void* d_ws, size_t ws_size,
                              hipStream_t stream) {
    const float* xyz1    = (const float*)d_in[0];
    const float* xyz2    = (const float*)d_in[1];
    const float* points1 = (const float*)d_in[2];
    const float* points2 = (const float*)d_in[3];
    const float* W       = (const float*)d_in[4];
    const float* bias    = (const float*)d_in[5];

    char* ws = (char*)d_ws;
    ushort*   Wfh     = (ushort*)(ws + WS_WFH);
    ushort*   Wfl     = (ushort*)(ws + WS_WFL);
    uint32_t* hist    = (uint32_t*)(ws + WS_HIST);
    float4*   sp_xyzn = (float4*)(ws + WS_SPXYZ);
    float4*   qs_xyzw = (float4*)(ws + WS_QSXYZ);
    ushort*   sp_idx  = (ushort*)(ws + WS_SPIDX);
    ushort*   qs_idx  = (ushort*)(ws + WS_QSIDX);
    uint32_t* gbU     = (uint32_t*)(ws + WS_GB);

    prep_w_kernel<<<192, 256, 0, stream>>>(W, Wfh, Wfl, hist, gbU);
    hist_kernel<<<128, 256, 0, stream>>>(xyz1, xyz2, hist);
    prefix_kernel<<<4, 1024, 0, stream>>>(hist);
    scatter_kernel<<<128, 256, 0, stream>>>(xyz1, xyz2, hist,
                                            sp_xyzn, qs_xyzw, sp_idx, qs_idx, gbU);
    fused_kernel<<<(BQ * NQ) / 16, 256, 0, stream>>>(
        sp_xyzn, sp_idx, qs_xyzw, qs_idx, points1, points2,
        Wfh, Wfl, bias, gbU, (float*)d_out);
}

// Round 4
// 152.692 us; speedup vs baseline: 1.1733x; 1.1733x over previous
//
#include <hip/hip_runtime.h>
#include <stdint.h>

// Problem constants (fixed by the reference)
#define BQ   2
#define NQ   8192
#define D1Q  128
#define D2Q  256
#define OUTQ 128
#define CATQ 384   // D1+D2
#define KQ   16

#define NBIN 4096          // 16x16x16 Morton cells
#define RED_MARGIN 1e-3f   // proxy-vs-exact bound margin (phase-1 threshold)
#define LB_MARGIN  1e-2f   // group-box lower-bound slack (covers all fp error)

// workspace byte offsets
#define WS_WFH   0          // ushort[49152]
#define WS_WFL   98304      // ushort[49152]
#define WS_SPXYZ 262144     // float4[2][8192] sorted points (x,y,z,npy-norm)
#define WS_QSXYZ 524288     // float4[2][8192] sorted queries (x,y,z,npy-s2)
#define WS_SPIDX 786432     // u16[2][8192] orig point idx
#define WS_QSIDX 819200     // u16[2][8192] orig query idx
#define WS_GBLO  851968     // float4[256] group AABB lo
#define WS_GBHI  856064     // float4[256] group AABB hi
// end: 860160 bytes

// bf16 split helpers (RNE)
__device__ __forceinline__ ushort f2bf(float f) {
    uint32_t u = __float_as_uint(f);
    return (ushort)((u + 0x7FFFu + ((u >> 16) & 1u)) >> 16);
}
__device__ __forceinline__ float bf2f(ushort h) {
    return __uint_as_float((uint32_t)h << 16);
}

// monotone float<->uint order map
__device__ __forceinline__ uint32_t encf(float f) {
    uint32_t b = __float_as_uint(f);
    return b ^ (0x80000000u | (uint32_t)((int32_t)b >> 31));
}
__device__ __forceinline__ float decf(uint32_t u) {
    uint32_t bits = (u & 0x80000000u) ? (u ^ 0x80000000u) : ~u;
    return __uint_as_float(bits);
}

__device__ __forceinline__ uint32_t mbcnt64(uint64_t m) {
    return __builtin_amdgcn_mbcnt_hi((uint32_t)(m >> 32),
           __builtin_amdgcn_mbcnt_lo((uint32_t)m, 0u));
}

typedef __attribute__((ext_vector_type(8))) short short8v;   // 8 bf16 (4 VGPRs)
typedef __attribute__((ext_vector_type(4))) float f32x4v;    // MFMA accumulator

// 4-bit/dim Morton bin (any binning is CORRECT; it only affects pruning rate)
__device__ __forceinline__ int mort_bin(float x, float y, float z) {
    int bx = (int)((x + 5.0f) * 1.6f); bx = bx < 0 ? 0 : (bx > 15 ? 15 : bx);
    int by = (int)((y + 5.0f) * 1.6f); by = by < 0 ? 0 : (by > 15 ? 15 : by);
    int bz = (int)((z + 5.0f) * 1.6f); bz = bz < 0 ? 0 : (bz > 15 ? 15 : bz);
    int k = 0;
    #pragma unroll
    for (int t = 0; t < 4; ++t)
        k |= (((bx >> t) & 1) << (3 * t)) | (((by >> t) & 1) << (3 * t + 1)) |
             (((bz >> t) & 1) << (3 * t + 2));
    return k;
}

// ---------------------------------------------------------------------------
// P0 (R17): ONE prep kernel.
//  blocks 0-3  : full LDS counting sort of one (batch, role) array of 8192
//                (hist -> scan -> scatter via LDS atomics) + fused group-AABB
//                (LDS atomicMin/Max on encoded floats; no global atomics, no
//                init pass, no gbox kernel). Within-bin order is atomic-
//                nondeterministic -- harmless: selection keys are exact and
//                order-independent; rank-15 bound valid for any window.
//  blocks 4-51 : W split to bf16 hi/lo in MFMA B-fragment layout.
// Replaces 4 kernels (prep_w, hist, prefix, scatter+gbox) -> 1.
// ---------------------------------------------------------------------------
__global__ __launch_bounds__(1024) void prep_all_kernel(
        const float* __restrict__ W,
        ushort* __restrict__ Wfh, ushort* __restrict__ Wfl,
        const float* __restrict__ xyz1, const float* __restrict__ xyz2,
        float4* __restrict__ sp_xyzn, float4* __restrict__ qs_xyzw,
        ushort* __restrict__ sp_idx, ushort* __restrict__ qs_idx,
        float4* __restrict__ gblo, float4* __restrict__ gbhi) {
    __shared__ uint32_t hist[NBIN];      // 16 KB
    __shared__ uint32_t sc[1024];        // 4 KB scan buffer
    __shared__ uint32_t ab[128 * 8];     // 4 KB enc'd AABBs (6 of 8 used)

    const int bid = blockIdx.x;
    const int tid = threadIdx.x;

    if (bid >= 4) {
        // ---- W split: flat over 48*1024 = CATQ*OUTQ ----
        int flat = (bid - 4) * 1024 + tid;
        if (flat < CATQ * OUTQ) {
            int r    = flat & 7;
            int lane = (flat >> 3) & 63;
            int ctk  = flat >> 9;
            int ct   = ctk & 7;
            int kt   = ctk >> 3;
            int o = ct * 16 + (lane & 15);
            int k = kt * 32 + (lane >> 4) * 8 + r;
            float v  = W[o * CATQ + k];
            ushort h = f2bf(v);
            Wfh[flat] = h;
            Wfl[flat] = f2bf(v - bf2f(h));
        }
        return;
    }

    const int  batch = bid & 1;
    const bool isPts = bid < 2;
    const float* src = (isPts ? xyz1 : xyz2) + (size_t)batch * NQ * 3;

    // zero hist (+ AABB init for point blocks)
    #pragma unroll
    for (int i = tid; i < NBIN; i += 1024) hist[i] = 0u;
    if (isPts) ab[tid] = ((tid & 7) >= 4) ? 0u : 0xFFFFFFFFu;
    __syncthreads();

    // read 8 elems (coalesced: idx = e*1024 + tid), histogram
    float x[8], y[8], z[8];
    int   bin[8];
    #pragma unroll
    for (int e = 0; e < 8; ++e) {
        int idx = e * 1024 + tid;
        const float* p = src + (size_t)idx * 3;
        x[e] = p[0]; y[e] = p[1]; z[e] = p[2];
        bin[e] = mort_bin(x[e], y[e], z[e]);
        atomicAdd(&hist[bin[e]], 1u);
    }
    __syncthreads();

    // exclusive scan over 4096 bins (4 per thread + block scan of 1024)
    uint32_t v0 = hist[4 * tid], v1 = hist[4 * tid + 1],
             v2 = hist[4 * tid + 2], v3 = hist[4 * tid + 3];
    uint32_t s = v0 + v1 + v2 + v3;
    sc[tid] = s;
    __syncthreads();
    for (int d = 1; d < 1024; d <<= 1) {
        uint32_t xx = (tid >= d) ? sc[tid - d] : 0u;
        __syncthreads();
        sc[tid] += xx;
        __syncthreads();
    }
    uint32_t excl = sc[tid] - s;
    hist[4 * tid]     = excl;
    hist[4 * tid + 1] = excl + v0;
    hist[4 * tid + 2] = excl + v0 + v1;
    hist[4 * tid + 3] = excl + v0 + v1 + v2;
    __syncthreads();

    // scatter (pos via LDS atomicAdd) + npy-exact norm + group AABB atomics
    #pragma unroll
    for (int e = 0; e < 8; ++e) {
        int idx = e * 1024 + tid;
        uint32_t pos = atomicAdd(&hist[bin[e]], 1u);
        float n;
        {
            #pragma clang fp contract(off)
            float px = x[e] * x[e], py = y[e] * y[e], pz = z[e] * z[e];
            n = (px + py) + pz;
        }
        if (isPts) {
            sp_xyzn[batch * NQ + pos] = make_float4(x[e], y[e], z[e], n);
            sp_idx[batch * NQ + pos]  = (ushort)idx;
            uint32_t* gw = ab + ((pos >> 6) << 3);
            atomicMin(&gw[0], encf(x[e]));
            atomicMin(&gw[1], encf(y[e]));
            atomicMin(&gw[2], encf(z[e]));
            atomicMax(&gw[4], encf(x[e]));
            atomicMax(&gw[5], encf(y[e]));
            atomicMax(&gw[6], encf(z[e]));
        } else {
            qs_xyzw[batch * NQ + pos] = make_float4(x[e], y[e], z[e], n);
            qs_idx[batch * NQ + pos]  = (ushort)idx;
        }
    }
    if (isPts) {
        __syncthreads();
        if (tid < 128) {
            gblo[batch * 128 + tid] = make_float4(
                decf(ab[tid * 8 + 0]), decf(ab[tid * 8 + 1]),
                decf(ab[tid * 8 + 2]), 0.f);
            gbhi[batch * 128 + tid] = make_float4(
                decf(ab[tid * 8 + 4]), decf(ab[tid * 8 + 5]),
                decf(ab[tid * 8 + 6]), 0.f);
        }
    }
}

// numpy-exact squared distance (same rounding as the reference BLAS path)
__device__ __forceinline__ float npy_d2(float4 pt, float qx, float qy, float qz,
                                        float s2) {
    #pragma clang fp contract(off)
    float d0  = pt.x * qx;                 // rounded product
    float dot = fmaf(pt.y, qy, d0);        // explicit FMA chain
    dot       = fmaf(pt.z, qz, dot);
    float tt  = s2 + pt.w;                 // rounded add
    return tt - 2.0f * dot;                // 2*dot exact; rounded sub
}

// 4-op reduced proxy: exact_d2 ~= s2 + red within ~1.5e-5. Phase-1 bound only.
__device__ __forceinline__ float red_r(float4 pt, float qx, float qy, float qz) {
    float dot = fmaf(pt.z, qz, fmaf(pt.y, qy, pt.x * qx));
    return fmaf(-2.0f, dot, pt.w);
}

// full ascending bitonic sort of one uint64 per lane across the wave
__device__ __forceinline__ uint64_t sort64(uint64_t x, int lane) {
    #pragma unroll
    for (int k = 2; k <= 64; k <<= 1) {
        #pragma unroll
        for (int j = k >> 1; j > 0; j >>= 1) {
            uint64_t p = __shfl_xor((unsigned long long)x, j, 64);
            bool keep_min = (((lane & j) == 0) == ((lane & k) == 0));
            bool pless    = p < x;
            x = (pless == keep_min) ? p : x;   // ties: same value either way
        }
    }
    return x;
}

// ---------------------------------------------------------------------------
// Fused kernel (R17): R16 + latency fixes.
//  vs R16 (counters: VALU fell 36->24% while time ROSE 76->84us -> phase-2
//  serial LDS->global->ballot chain was latency-bound, not compute-bound):
//  - Phase 2 keeps per-wave survivor lists + direct global reads, but adds a
//    DEPTH-2 SOFTWARE PIPELINE: groups i+1, i+2 are in flight while group i
//    computes (~300cyc compute covers L2 latency).
//  - Bijective XCD swizzle (1024 blocks % 8 == 0): Morton-neighbor blocks
//    share points2 gather rows -> same-XCD L2 reuse (FETCH_SIZE was 80MB vs
//    ~27MB of inputs).
//  - Phase-1 unroll 4 -> 8 (more independent loads in flight).
//  - gblo/gbhi as plain float4 (written race-free by prep block).
//  Selection + stages 2-3 bit-identical.
// ---------------------------------------------------------------------------
__global__ __launch_bounds__(256, 4) void fused_kernel(
        const float4* __restrict__ sp_xyzn, const ushort* __restrict__ sp_idx,
        const float4* __restrict__ qs_xyzw, const ushort* __restrict__ qs_idx,
        const float* __restrict__ points1, const float* __restrict__ points2,
        const ushort* __restrict__ Wfh, const ushort* __restrict__ Wfl,
        const float* __restrict__ bias,
        const float4* __restrict__ gblo, const float4* __restrict__ gbhi,
        float* __restrict__ out) {
    __shared__ __align__(16) char smem[26368];
    uint64_t* wball = (uint64_t*)smem;               // [0,16K) per-wave rows
    ushort*   cat_h = (ushort*)smem;                 // [0,12544)   stages 2-3
    ushort*   cat_l = (ushort*)(smem + 12544);       // [12544,25088)
    ushort*   slist = (ushort*)(smem + 25088);       // [25088,26112) [4][128]
    ushort*   qsl   = (ushort*)(smem + 26112);       // [16] orig query idx

    const int tid   = threadIdx.x;
    const int lane  = tid & 63;
    const int w     = tid >> 6;
    // bijective XCD swizzle: 1024 blocks, 8 XCDs, 128 contiguous per XCD
    const int blk   = (blockIdx.x & 7) * 128 + (blockIdx.x >> 3);
    const int b     = blk >> 9;                     // batch
    const int qslot = (blk & 511) * 16;             // sorted-query base

    if (tid < 16) qsl[tid] = qs_idx[b * NQ + qslot + tid];

    // wave's 4 sorted queries (s2 precomputed npy-exact)
    float qx[4], qy[4], qz[4], s2[4];
    int   oqi[4];
    #pragma unroll
    for (int j = 0; j < 4; ++j) {
        float4 q = qs_xyzw[(size_t)b * NQ + qslot + w * 4 + j];
        qx[j] = q.x; qy[j] = q.y; qz[j] = q.z; s2[j] = q.w;
        oqi[j] = (int)qs_idx[b * NQ + qslot + w * 4 + j];
    }

    const float4* spb = sp_xyzn + (size_t)b * NQ;
    const ushort* spi = sp_idx  + (size_t)b * NQ;

    // ------- Phase 1: proxy lane-min over a 1024-pt window (global direct) ----
    int wstart = qslot + 8 - 512;
    if (wstart < 0) wstart = 0;
    if (wstart > NQ - 1024) wstart = NQ - 1024;
    wstart &= ~63;
    const float4* win = spb + wstart;

    float mn[4];
    #pragma unroll
    for (int j = 0; j < 4; ++j) mn[j] = __uint_as_float(0x7F800000u);

    #pragma unroll 8
    for (int s = 0; s < 16; ++s) {
        float4 pt = win[s * 64 + lane];
        #pragma unroll
        for (int j = 0; j < 4; ++j)
            mn[j] = fminf(mn[j], red_r(pt, qx[j], qy[j], qz[j]));
    }

    // 4 float bitonic sorts of lane minima; that[j] = s2 + rank15 + margin
    float that[4];
    #pragma unroll
    for (int j = 0; j < 4; ++j) {
        float x = mn[j];
        #pragma unroll
        for (int k = 2; k <= 64; k <<= 1) {
            #pragma unroll
            for (int jj = k >> 1; jj > 0; jj >>= 1) {
                float px = __shfl_xor(x, jj, 64);
                bool keep_min = (((lane & jj) == 0) == ((lane & k) == 0));
                float mnv = fminf(x, px), mxv = fmaxf(x, px);
                x = keep_min ? mnv : mxv;
            }
        }
        that[j] = s2[j] + __shfl(x, 15, 64) + RED_MARGIN;
    }

    // ------- per-WAVE group-box test (uniform math; ballot compaction) -------
    ushort* sl = slist + w * 128;
    int scnt_w = 0;
    {
        float qlx = fminf(fminf(qx[0], qx[1]), fminf(qx[2], qx[3]));
        float qly = fminf(fminf(qy[0], qy[1]), fminf(qy[2], qy[3]));
        float qlz = fminf(fminf(qz[0], qz[1]), fminf(qz[2], qz[3]));
        float qhx = fmaxf(fmaxf(qx[0], qx[1]), fmaxf(qx[2], qx[3]));
        float qhy = fmaxf(fmaxf(qy[0], qy[1]), fmaxf(qy[2], qy[3]));
        float qhz = fmaxf(fmaxf(qz[0], qz[1]), fmaxf(qz[2], qz[3]));
        float tmax = fmaxf(fmaxf(that[0], that[1]), fmaxf(that[2], that[3]))
                   + LB_MARGIN;
        #pragma unroll
        for (int h = 0; h < 2; ++h) {
            int g = h * 64 + lane;
            float4 gl = gblo[b * 128 + g];
            float4 gh = gbhi[b * 128 + g];
            float dx = fmaxf(fmaxf(qlx - gh.x, gl.x - qhx), 0.f);
            float dy = fmaxf(fmaxf(qly - gh.y, gl.y - qhy), 0.f);
            float dz = fmaxf(fmaxf(qlz - gh.z, gl.z - qhz), 0.f);
            float lb = dx * dx;
            lb = fmaf(dy, dy, lb);
            lb = fmaf(dz, dz, lb);
            bool sv = (lb <= tmax);
            uint64_t m = __ballot((int)sv);
            if (sv) sl[scnt_w + mbcnt64(m)] = (ushort)g;
            scnt_w += (int)__popcll(m);
        }
    }

    // ------- Phase 2: exact scan, DEPTH-2 pipelined global loads -------
    uint32_t cnt[4] = {0u, 0u, 0u, 0u};
    {
        float4 ptA = make_float4(0.f, 0.f, 0.f, 0.f), ptB = ptA;
        uint32_t pA = 0u, pB = 0u;
        if (scnt_w > 0) {
            int g = (int)sl[0];
            ptA = spb[g * 64 + lane]; pA = (uint32_t)spi[g * 64 + lane];
        }
        if (scnt_w > 1) {
            int g = (int)sl[1];
            ptB = spb[g * 64 + lane]; pB = (uint32_t)spi[g * 64 + lane];
        }
        for (int i = 0; i < scnt_w; ++i) {
            float4   pt   = ptA;
            uint32_t pidx = pA;
            ptA = ptB; pA = pB;
            if (i + 2 < scnt_w) {                  // issue loads 2 ahead
                int g = (int)sl[i + 2];
                ptB = spb[g * 64 + lane];
                pB  = (uint32_t)spi[g * 64 + lane];
            }
            #pragma unroll
            for (int j = 0; j < 4; ++j) {
                float d2 = npy_d2(pt, qx[j], qy[j], qz[j], s2[j]);
                bool  v  = (d2 <= that[j]);
                uint64_t mask = __ballot((int)v);
                if (mask != 0ull) {                // scalar gate
                    if (v) {
                        uint32_t pos    = cnt[j] + mbcnt64(mask);
                        uint32_t bits   = __float_as_uint(d2);
                        uint32_t mapped = bits ^ (0x80000000u |
                                          (uint32_t)((int32_t)bits >> 31));
                        if (pos < 128u)
                            wball[(w * 4 + j) * 128 + pos] =
                                ((uint64_t)mapped << 32) | (uint64_t)pidx;
                    }
                    cnt[j] += (uint32_t)__popcll(mask);
                }
            }
        }
    }

    // ---------------- per-query selection + weights (unchanged) ----------------
    int   myidxA[4];
    float mywgtA[4];
    #pragma unroll
    for (int j = 0; j < 4; ++j) {
        const uint64_t* wb = wball + (size_t)(w * 4 + j) * 128;
        const uint32_t c = cnt[j];
        uint64_t mykey;
        if (c <= 64u) {                            // normal path
            uint64_t k0 = (lane < (int)c) ? wb[lane] : ~0ull;
            mykey = sort64(k0, lane);
        } else {                                   // uniform fallback
            uint32_t cc = c > 128u ? 128u : c;
            uint64_t k0 = wb[lane];
            uint64_t k1 = (lane + 64 < (int)cc) ? wb[lane + 64] : ~0ull;
            k0 = sort64(k0, lane);
            k1 = sort64(k1, lane);
            uint64_t t1 = __shfl((unsigned long long)k1, lane & 15, 64);
            uint64_t km = (lane < 16) ? k0 : ((lane < 32) ? t1 : ~0ull);
            mykey = sort64(km, lane);
        }
        uint32_t mhi   = (uint32_t)(mykey >> 32);
        uint32_t rbits = (mhi & 0x80000000u) ? (mhi ^ 0x80000000u) : ~mhi;
        float    d2w   = __uint_as_float(rbits);
        myidxA[j] = (int)(uint32_t)(mykey & 0xFFFFFFFFull);
        float recip = (lane < KQ) ? (1.0f / (d2w + 1e-8f)) : 0.0f;
        float tot = recip;
        #pragma unroll
        for (int sh = 1; sh < 16; sh <<= 1) tot += __shfl_xor(tot, sh, 64);
        mywgtA[j] = recip / tot;                   // valid in lanes 0..15
    }

    // LDS reuse boundary: all waves done reading wball before cat overwrites it
    __syncthreads();

    // ------- Stage 2: build cat (bf16 hi/lo split) [16][392] in LDS -------
    const float* p2b = points2 + (size_t)b * NQ * D2Q;
    #pragma unroll
    for (int j = 0; j < 4; ++j) {
        const int qi = w * 4 + j;
        // p1 part: 128 floats, lanes 0..31 (orig query row via permutation)
        if (lane < 32) {
            float4 p = ((const float4*)(points1 +
                        (size_t)(b * NQ + oqi[j]) * D1Q))[lane];
            ushort4 hv, lv;
            hv.x = f2bf(p.x); lv.x = f2bf(p.x - bf2f(hv.x));
            hv.y = f2bf(p.y); lv.y = f2bf(p.y - bf2f(hv.y));
            hv.z = f2bf(p.z); lv.z = f2bf(p.z - bf2f(hv.z));
            hv.w = f2bf(p.w); lv.w = f2bf(p.w - bf2f(hv.w));
            *(ushort4*)&cat_h[qi * 392 + lane * 4] = hv;
            *(ushort4*)&cat_l[qi * 392 + lane * 4] = lv;
        }
        // interp part: 256 floats, all 64 lanes; k ascending (reference order)
        float4 acc = make_float4(0.f, 0.f, 0.f, 0.f);
        #pragma unroll
        for (int k = 0; k < KQ; ++k) {
            int   kk = __builtin_amdgcn_readlane(myidxA[j], k);
            float wk = __uint_as_float((uint32_t)__builtin_amdgcn_readlane(
                           (int)__float_as_uint(mywgtA[j]), k));
            float4 row = ((const float4*)(p2b + (size_t)kk * D2Q))[lane];
            acc.x = fmaf(wk, row.x, acc.x);
            acc.y = fmaf(wk, row.y, acc.y);
            acc.z = fmaf(wk, row.z, acc.z);
            acc.w = fmaf(wk, row.w, acc.w);
        }
        {
            ushort4 hv, lv;
            hv.x = f2bf(acc.x); lv.x = f2bf(acc.x - bf2f(hv.x));
            hv.y = f2bf(acc.y); lv.y = f2bf(acc.y - bf2f(hv.y));
            hv.z = f2bf(acc.z); lv.z = f2bf(acc.z - bf2f(hv.z));
            hv.w = f2bf(acc.w); lv.w = f2bf(acc.w - bf2f(hv.w));
            *(ushort4*)&cat_h[qi * 392 + D1Q + lane * 4] = hv;
            *(ushort4*)&cat_l[qi * 392 + D1Q + lane * 4] = lv;
        }
    }
    __syncthreads();

    // ------- Stage 3: MFMA GEMM  C[16][128] = cat[16][384] @ Wt[384][128] -------
    {
        const int arow = lane & 15;
        const int koff = (lane >> 4) * 8;
        const int ct0  = w * 2;
        f32x4v acc0 = {0.f, 0.f, 0.f, 0.f};
        f32x4v acc1 = {0.f, 0.f, 0.f, 0.f};
        #pragma unroll 4
        for (int kt = 0; kt < 12; ++kt) {
            short8v ah = *(const short8v*)&cat_h[arow * 392 + kt * 32 + koff];
            short8v al = *(const short8v*)&cat_l[arow * 392 + kt * 32 + koff];
            const ushort* bhp = Wfh + ((size_t)(kt * 8 + ct0) * 64 + lane) * 8;
            const ushort* blp = Wfl + ((size_t)(kt * 8 + ct0) * 64 + lane) * 8;
            short8v bh0 = *(const short8v*)bhp;
            short8v bl0 = *(const short8v*)blp;
            short8v bh1 = *(const short8v*)(bhp + 512);
            short8v bl1 = *(const short8v*)(blp + 512);
            acc0 = __builtin_amdgcn_mfma_f32_16x16x32_bf16(ah, bh0, acc0, 0, 0, 0);
            acc0 = __builtin_amdgcn_mfma_f32_16x16x32_bf16(al, bh0, acc0, 0, 0, 0);
            acc0 = __builtin_amdgcn_mfma_f32_16x16x32_bf16(ah, bl0, acc0, 0, 0, 0);
            acc1 = __builtin_amdgcn_mfma_f32_16x16x32_bf16(ah, bh1, acc1, 0, 0, 0);
            acc1 = __builtin_amdgcn_mfma_f32_16x16x32_bf16(al, bh1, acc1, 0, 0, 0);
            acc1 = __builtin_amdgcn_mfma_f32_16x16x32_bf16(ah, bl1, acc1, 0, 0, 0);
        }
        // C/D layout: col = lane&15, row = (lane>>4)*4 + r (m89-verified);
        // rows scatter through the query permutation.
        const int col0   = ct0 * 16 + (lane & 15);
        const int r0slot = (lane >> 4) * 4;
        const float bv0 = bias[col0];
        const float bv1 = bias[col0 + 16];
        #pragma unroll
        for (int r = 0; r < 4; ++r) {
            int oq = (int)qsl[r0slot + r];
            size_t rowoff = (size_t)(b * NQ + oq) * OUTQ;
            out[rowoff + col0]      = acc0[r] + bv0;
            out[rowoff + col0 + 16] = acc1[r] + bv1;
        }
    }
}

// ---------------------------------------------------------------------------
// Launch
// ---------------------------------------------------------------------------
extern "C" void kernel_launch(void* const* d_in, const int* in_sizes, int n_in,
                              void* d_out, int out_size, void* d_ws, size_t ws_size,
                              hipStream_t stream) {
    const float* xyz1    = (const float*)d_in[0];
    const float* xyz2    = (const float*)d_in[1];
    const float* points1 = (const float*)d_in[2];
    const float* points2 = (const float*)d_in[3];
    const float* W       = (const float*)d_in[4];
    const float* bias    = (const float*)d_in[5];

    char* ws = (char*)d_ws;
    ushort*   Wfh     = (ushort*)(ws + WS_WFH);
    ushort*   Wfl     = (ushort*)(ws + WS_WFL);
    float4*   sp_xyzn = (float4*)(ws + WS_SPXYZ);
    float4*   qs_xyzw = (float4*)(ws + WS_QSXYZ);
    ushort*   sp_idx  = (ushort*)(ws + WS_SPIDX);
    ushort*   qs_idx  = (ushort*)(ws + WS_QSIDX);
    float4*   gblo    = (float4*)(ws + WS_GBLO);
    float4*   gbhi    = (float4*)(ws + WS_GBHI);

    prep_all_kernel<<<52, 1024, 0, stream>>>(W, Wfh, Wfl, xyz1, xyz2,
                                             sp_xyzn, qs_xyzw, sp_idx, qs_idx,
                                             gblo, gbhi);
    fused_kernel<<<(BQ * NQ) / 16, 256, 0, stream>>>(
        sp_xyzn, sp_idx, qs_xyzw, qs_idx, points1, points2,
        Wfh, Wfl, bias, gblo, gbhi, (float*)d_out);
}

// Round 5
// 150.379 us; speedup vs baseline: 1.1914x; 1.0154x over previous
//
#include <hip/hip_runtime.h>
#include <stdint.h>

// Problem constants (fixed by the reference)
#define BQ   2
#define NQ   8192
#define D1Q  128
#define D2Q  256
#define OUTQ 128
#define CATQ 384   // D1+D2
#define KQ   16

#define NBIN 4096          // 16x16x16 Morton cells
#define RED_MARGIN 1e-3f   // proxy-vs-exact bound margin (phase-1 threshold)
#define LB_MARGIN  1e-2f   // group-box lower-bound slack (covers all fp error)

// Per-wave LDS region (bytes). Holds EITHER phase-A state (wball 4096 +
// slist 256) OR phase-B state (cat_h 3136 + cat_l 3136). 6448 = 403*16
// (16B aligned); non-multiple-of-128 to spread banks across regions.
#define WREG 6448

// workspace byte offsets
#define WS_WFH   0          // ushort[49152]
#define WS_WFL   98304      // ushort[49152]
#define WS_SPXYZ 262144     // float4[2][8192] sorted points (x,y,z,npy-norm)
#define WS_QSXYZ 524288     // float4[2][8192] sorted queries (x,y,z,npy-s2)
#define WS_SPIDX 786432     // u16[2][8192] orig point idx
#define WS_QSIDX 819200     // u16[2][8192] orig query idx
#define WS_GBLO  851968     // float4[256] group AABB lo
#define WS_GBHI  856064     // float4[256] group AABB hi
// end: 860160 bytes

// bf16 split helpers (RNE)
__device__ __forceinline__ ushort f2bf(float f) {
    uint32_t u = __float_as_uint(f);
    return (ushort)((u + 0x7FFFu + ((u >> 16) & 1u)) >> 16);
}
__device__ __forceinline__ float bf2f(ushort h) {
    return __uint_as_float((uint32_t)h << 16);
}

// monotone float<->uint order map
__device__ __forceinline__ uint32_t encf(float f) {
    uint32_t b = __float_as_uint(f);
    return b ^ (0x80000000u | (uint32_t)((int32_t)b >> 31));
}
__device__ __forceinline__ float decf(uint32_t u) {
    uint32_t bits = (u & 0x80000000u) ? (u ^ 0x80000000u) : ~u;
    return __uint_as_float(bits);
}

__device__ __forceinline__ uint32_t mbcnt64(uint64_t m) {
    return __builtin_amdgcn_mbcnt_hi((uint32_t)(m >> 32),
           __builtin_amdgcn_mbcnt_lo((uint32_t)m, 0u));
}

typedef __attribute__((ext_vector_type(8))) short short8v;   // 8 bf16 (4 VGPRs)
typedef __attribute__((ext_vector_type(4))) float f32x4v;    // MFMA accumulator

// 4-bit/dim Morton bin (any binning is CORRECT; it only affects pruning rate)
__device__ __forceinline__ int mort_bin(float x, float y, float z) {
    int bx = (int)((x + 5.0f) * 1.6f); bx = bx < 0 ? 0 : (bx > 15 ? 15 : bx);
    int by = (int)((y + 5.0f) * 1.6f); by = by < 0 ? 0 : (by > 15 ? 15 : by);
    int bz = (int)((z + 5.0f) * 1.6f); bz = bz < 0 ? 0 : (bz > 15 ? 15 : bz);
    int k = 0;
    #pragma unroll
    for (int t = 0; t < 4; ++t)
        k |= (((bx >> t) & 1) << (3 * t)) | (((by >> t) & 1) << (3 * t + 1)) |
             (((bz >> t) & 1) << (3 * t + 2));
    return k;
}

// ---------------------------------------------------------------------------
// P0 (R18): ONE prep kernel, faster sort path.
//  blocks 0-3  : LDS counting sort of one (batch, role) array of 8192.
//                vs R17: the 4096-bin exclusive scan is now a shfl-based
//                hierarchical scan (wave-scan + 16-partial scan) -> 4 block
//                barriers total instead of 22 at 1024 threads.
//  blocks 4-51 : W split to bf16 hi/lo in MFMA B-fragment layout.
// ---------------------------------------------------------------------------
__global__ __launch_bounds__(1024) void prep_all_kernel(
        const float* __restrict__ W,
        ushort* __restrict__ Wfh, ushort* __restrict__ Wfl,
        const float* __restrict__ xyz1, const float* __restrict__ xyz2,
        float4* __restrict__ sp_xyzn, float4* __restrict__ qs_xyzw,
        ushort* __restrict__ sp_idx, ushort* __restrict__ qs_idx,
        float4* __restrict__ gblo, float4* __restrict__ gbhi) {
    __shared__ uint32_t hist[NBIN];      // 16 KB
    __shared__ uint32_t sc[16];          // wave partial sums
    __shared__ uint32_t ab[128 * 8];     // 4 KB enc'd AABBs (6 of 8 used)

    const int bid = blockIdx.x;
    const int tid = threadIdx.x;

    if (bid >= 4) {
        // ---- W split: flat over 48*1024 = CATQ*OUTQ ----
        int flat = (bid - 4) * 1024 + tid;
        if (flat < CATQ * OUTQ) {
            int r    = flat & 7;
            int lane = (flat >> 3) & 63;
            int ctk  = flat >> 9;
            int ct   = ctk & 7;
            int kt   = ctk >> 3;
            int o = ct * 16 + (lane & 15);
            int k = kt * 32 + (lane >> 4) * 8 + r;
            float v  = W[o * CATQ + k];
            ushort h = f2bf(v);
            Wfh[flat] = h;
            Wfl[flat] = f2bf(v - bf2f(h));
        }
        return;
    }

    const int  batch = bid & 1;
    const bool isPts = bid < 2;
    const float* src = (isPts ? xyz1 : xyz2) + (size_t)batch * NQ * 3;

    // zero hist (+ AABB init for point blocks)
    #pragma unroll
    for (int i = tid; i < NBIN; i += 1024) hist[i] = 0u;
    if (isPts) ab[tid] = ((tid & 7) >= 4) ? 0u : 0xFFFFFFFFu;
    __syncthreads();

    // read 8 elems (coalesced: idx = e*1024 + tid), histogram
    float x[8], y[8], z[8];
    int   bin[8];
    #pragma unroll
    for (int e = 0; e < 8; ++e) {
        int idx = e * 1024 + tid;
        const float* p = src + (size_t)idx * 3;
        x[e] = p[0]; y[e] = p[1]; z[e] = p[2];
        bin[e] = mort_bin(x[e], y[e], z[e]);
        atomicAdd(&hist[bin[e]], 1u);
    }
    __syncthreads();

    // exclusive scan over 4096 bins: 4/thread + wave shfl-scan + 16-part scan
    uint32_t v0 = hist[4 * tid], v1 = hist[4 * tid + 1],
             v2 = hist[4 * tid + 2], v3 = hist[4 * tid + 3];
    uint32_t s = v0 + v1 + v2 + v3;
    uint32_t incl = s;
    #pragma unroll
    for (int d = 1; d < 64; d <<= 1) {
        uint32_t t = __shfl_up(incl, d, 64);
        if ((tid & 63) >= d) incl += t;
    }
    if ((tid & 63) == 63) sc[tid >> 6] = incl;
    __syncthreads();
    if (tid < 16) {
        uint32_t v = sc[tid];
        uint32_t i2 = v;
        #pragma unroll
        for (int d = 1; d < 16; d <<= 1) {
            uint32_t t = __shfl_up(i2, d, 64);
            if (tid >= d) i2 += t;
        }
        sc[tid] = i2 - v;                  // exclusive wave offset
    }
    __syncthreads();
    uint32_t excl = sc[tid >> 6] + (incl - s);
    hist[4 * tid]     = excl;
    hist[4 * tid + 1] = excl + v0;
    hist[4 * tid + 2] = excl + v0 + v1;
    hist[4 * tid + 3] = excl + v0 + v1 + v2;
    __syncthreads();

    // scatter (pos via LDS atomicAdd) + npy-exact norm + group AABB atomics
    #pragma unroll
    for (int e = 0; e < 8; ++e) {
        int idx = e * 1024 + tid;
        uint32_t pos = atomicAdd(&hist[bin[e]], 1u);
        float n;
        {
            #pragma clang fp contract(off)
            float px = x[e] * x[e], py = y[e] * y[e], pz = z[e] * z[e];
            n = (px + py) + pz;
        }
        if (isPts) {
            sp_xyzn[batch * NQ + pos] = make_float4(x[e], y[e], z[e], n);
            sp_idx[batch * NQ + pos]  = (ushort)idx;
            uint32_t* gw = ab + ((pos >> 6) << 3);
            atomicMin(&gw[0], encf(x[e]));
            atomicMin(&gw[1], encf(y[e]));
            atomicMin(&gw[2], encf(z[e]));
            atomicMax(&gw[4], encf(x[e]));
            atomicMax(&gw[5], encf(y[e]));
            atomicMax(&gw[6], encf(z[e]));
        } else {
            qs_xyzw[batch * NQ + pos] = make_float4(x[e], y[e], z[e], n);
            qs_idx[batch * NQ + pos]  = (ushort)idx;
        }
    }
    if (isPts) {
        __syncthreads();
        if (tid < 128) {
            gblo[batch * 128 + tid] = make_float4(
                decf(ab[tid * 8 + 0]), decf(ab[tid * 8 + 1]),
                decf(ab[tid * 8 + 2]), 0.f);
            gbhi[batch * 128 + tid] = make_float4(
                decf(ab[tid * 8 + 4]), decf(ab[tid * 8 + 5]),
                decf(ab[tid * 8 + 6]), 0.f);
        }
    }
}

// numpy-exact squared distance (same rounding as the reference BLAS path)
__device__ __forceinline__ float npy_d2(float4 pt, float qx, float qy, float qz,
                                        float s2) {
    #pragma clang fp contract(off)
    float d0  = pt.x * qx;                 // rounded product
    float dot = fmaf(pt.y, qy, d0);        // explicit FMA chain
    dot       = fmaf(pt.z, qz, dot);
    float tt  = s2 + pt.w;                 // rounded add
    return tt - 2.0f * dot;                // 2*dot exact; rounded sub
}

// 4-op reduced proxy: exact_d2 ~= s2 + red within ~1.5e-5. Phase-1 bound only.
__device__ __forceinline__ float red_r(float4 pt, float qx, float qy, float qz) {
    float dot = fmaf(pt.z, qz, fmaf(pt.y, qy, pt.x * qx));
    return fmaf(-2.0f, dot, pt.w);
}

// full ascending bitonic sort of one uint64 per lane across the wave
__device__ __forceinline__ uint64_t sort64(uint64_t x, int lane) {
    #pragma unroll
    for (int k = 2; k <= 64; k <<= 1) {
        #pragma unroll
        for (int j = k >> 1; j > 0; j >>= 1) {
            uint64_t p = __shfl_xor((unsigned long long)x, j, 64);
            bool keep_min = (((lane & j) == 0) == ((lane & k) == 0));
            bool pless    = p < x;
            x = (pless == keep_min) ? p : x;   // ties: same value either way
        }
    }
    return x;
}

// ---------------------------------------------------------------------------
// Fused kernel (R18): wave-private LDS regions -> mid barrier REMOVED.
//  vs R17 (counters: VALU 31%, HBM 5%, occ 26%, fused 66us -> still ~3x
//  latency/imbalance slack; the selection->stage2 __syncthreads forced every
//  wave to wait for the block's slowest phase-2 scanner BEFORE starting the
//  heaviest memory phase (64KB/wave points2 gather)):
//  - Each wave owns a private 6448B LDS region: phase A = its wball[4][128]
//    + slist[128]; phase B = its cat_h[4][392] + cat_l[4][392]. The
//    wball->cat overwrite is now WAVE-LOCAL, so each wave transitions as soon
//    as ITS selection is done -- fast waves' gathers overlap slow waves'
//    scans. Exactly ONE __syncthreads remains (pre-GEMM, true cross-wave dep).
//  - Stage-3 A-fragment addressing goes through the region map:
//    row r lives at (r>>2)*WREG + (r&3)*784 (+3136 for lo).
//  Selection + stages 2-3 numerics bit-identical.
// ---------------------------------------------------------------------------
__global__ __launch_bounds__(256, 4) void fused_kernel(
        const float4* __restrict__ sp_xyzn, const ushort* __restrict__ sp_idx,
        const float4* __restrict__ qs_xyzw, const ushort* __restrict__ qs_idx,
        const float* __restrict__ points1, const float* __restrict__ points2,
        const ushort* __restrict__ Wfh, const ushort* __restrict__ Wfl,
        const float* __restrict__ bias,
        const float4* __restrict__ gblo, const float4* __restrict__ gbhi,
        float* __restrict__ out) {
    __shared__ __align__(16) char smem[4 * WREG + 32];
    ushort* qsl = (ushort*)(smem + 4 * WREG);        // [16] orig query idx

    const int tid   = threadIdx.x;
    const int lane  = tid & 63;
    const int w     = tid >> 6;
    // bijective XCD swizzle: 1024 blocks, 8 XCDs, 128 contiguous per XCD
    const int blk   = (blockIdx.x & 7) * 128 + (blockIdx.x >> 3);
    const int b     = blk >> 9;                     // batch
    const int qslot = (blk & 511) * 16;             // sorted-query base

    char*     myreg   = smem + w * WREG;            // wave-private region
    uint64_t* wball_w = (uint64_t*)myreg;           // phase A: [4][128]
    ushort*   sl      = (ushort*)(myreg + 4096);    // phase A: [128]

    if (tid < 16) qsl[tid] = qs_idx[b * NQ + qslot + tid];

    // wave's 4 sorted queries (s2 precomputed npy-exact)
    float qx[4], qy[4], qz[4], s2[4];
    int   oqi[4];
    #pragma unroll
    for (int j = 0; j < 4; ++j) {
        float4 q = qs_xyzw[(size_t)b * NQ + qslot + w * 4 + j];
        qx[j] = q.x; qy[j] = q.y; qz[j] = q.z; s2[j] = q.w;
        oqi[j] = (int)qs_idx[b * NQ + qslot + w * 4 + j];
    }

    const float4* spb = sp_xyzn + (size_t)b * NQ;
    const ushort* spi = sp_idx  + (size_t)b * NQ;

    // ------- Phase 1: proxy lane-min over a 1024-pt window (global direct) ----
    int wstart = qslot + 8 - 512;
    if (wstart < 0) wstart = 0;
    if (wstart > NQ - 1024) wstart = NQ - 1024;
    wstart &= ~63;
    const float4* win = spb + wstart;

    float mn[4];
    #pragma unroll
    for (int j = 0; j < 4; ++j) mn[j] = __uint_as_float(0x7F800000u);

    #pragma unroll 8
    for (int s = 0; s < 16; ++s) {
        float4 pt = win[s * 64 + lane];
        #pragma unroll
        for (int j = 0; j < 4; ++j)
            mn[j] = fminf(mn[j], red_r(pt, qx[j], qy[j], qz[j]));
    }

    // 4 float bitonic sorts of lane minima; that[j] = s2 + rank15 + margin
    float that[4];
    #pragma unroll
    for (int j = 0; j < 4; ++j) {
        float x = mn[j];
        #pragma unroll
        for (int k = 2; k <= 64; k <<= 1) {
            #pragma unroll
            for (int jj = k >> 1; jj > 0; jj >>= 1) {
                float px = __shfl_xor(x, jj, 64);
                bool keep_min = (((lane & jj) == 0) == ((lane & k) == 0));
                float mnv = fminf(x, px), mxv = fmaxf(x, px);
                x = keep_min ? mnv : mxv;
            }
        }
        that[j] = s2[j] + __shfl(x, 15, 64) + RED_MARGIN;
    }

    // ------- per-WAVE group-box test (uniform math; ballot compaction) -------
    int scnt_w = 0;
    {
        float qlx = fminf(fminf(qx[0], qx[1]), fminf(qx[2], qx[3]));
        float qly = fminf(fminf(qy[0], qy[1]), fminf(qy[2], qy[3]));
        float qlz = fminf(fminf(qz[0], qz[1]), fminf(qz[2], qz[3]));
        float qhx = fmaxf(fmaxf(qx[0], qx[1]), fmaxf(qx[2], qx[3]));
        float qhy = fmaxf(fmaxf(qy[0], qy[1]), fmaxf(qy[2], qy[3]));
        float qhz = fmaxf(fmaxf(qz[0], qz[1]), fmaxf(qz[2], qz[3]));
        float tmax = fmaxf(fmaxf(that[0], that[1]), fmaxf(that[2], that[3]))
                   + LB_MARGIN;
        #pragma unroll
        for (int h = 0; h < 2; ++h) {
            int g = h * 64 + lane;
            float4 gl = gblo[b * 128 + g];
            float4 gh = gbhi[b * 128 + g];
            float dx = fmaxf(fmaxf(qlx - gh.x, gl.x - qhx), 0.f);
            float dy = fmaxf(fmaxf(qly - gh.y, gl.y - qhy), 0.f);
            float dz = fmaxf(fmaxf(qlz - gh.z, gl.z - qhz), 0.f);
            float lb = dx * dx;
            lb = fmaf(dy, dy, lb);
            lb = fmaf(dz, dz, lb);
            bool sv = (lb <= tmax);
            uint64_t m = __ballot((int)sv);
            if (sv) sl[scnt_w + mbcnt64(m)] = (ushort)g;
            scnt_w += (int)__popcll(m);
        }
    }

    // ------- Phase 2: exact scan, DEPTH-2 pipelined global loads -------
    uint32_t cnt[4] = {0u, 0u, 0u, 0u};
    {
        float4 ptA = make_float4(0.f, 0.f, 0.f, 0.f), ptB = ptA;
        uint32_t pA = 0u, pB = 0u;
        if (scnt_w > 0) {
            int g = (int)sl[0];
            ptA = spb[g * 64 + lane]; pA = (uint32_t)spi[g * 64 + lane];
        }
        if (scnt_w > 1) {
            int g = (int)sl[1];
            ptB = spb[g * 64 + lane]; pB = (uint32_t)spi[g * 64 + lane];
        }
        for (int i = 0; i < scnt_w; ++i) {
            float4   pt   = ptA;
            uint32_t pidx = pA;
            ptA = ptB; pA = pB;
            if (i + 2 < scnt_w) {                  // issue loads 2 ahead
                int g = (int)sl[i + 2];
                ptB = spb[g * 64 + lane];
                pB  = (uint32_t)spi[g * 64 + lane];
            }
            #pragma unroll
            for (int j = 0; j < 4; ++j) {
                float d2 = npy_d2(pt, qx[j], qy[j], qz[j], s2[j]);
                bool  v  = (d2 <= that[j]);
                uint64_t mask = __ballot((int)v);
                if (mask != 0ull) {                // scalar gate
                    if (v) {
                        uint32_t pos    = cnt[j] + mbcnt64(mask);
                        uint32_t bits   = __float_as_uint(d2);
                        uint32_t mapped = bits ^ (0x80000000u |
                                          (uint32_t)((int32_t)bits >> 31));
                        if (pos < 128u)
                            wball_w[j * 128 + pos] =
                                ((uint64_t)mapped << 32) | (uint64_t)pidx;
                    }
                    cnt[j] += (uint32_t)__popcll(mask);
                }
            }
        }
    }

    // ---------------- per-query selection + weights (unchanged) ----------------
    int   myidxA[4];
    float mywgtA[4];
    #pragma unroll
    for (int j = 0; j < 4; ++j) {
        const uint64_t* wb = wball_w + (size_t)j * 128;
        const uint32_t c = cnt[j];
        uint64_t mykey;
        if (c <= 64u) {                            // normal path
            uint64_t k0 = (lane < (int)c) ? wb[lane] : ~0ull;
            mykey = sort64(k0, lane);
        } else {                                   // uniform fallback
            uint32_t cc = c > 128u ? 128u : c;
            uint64_t k0 = wb[lane];
            uint64_t k1 = (lane + 64 < (int)cc) ? wb[lane + 64] : ~0ull;
            k0 = sort64(k0, lane);
            k1 = sort64(k1, lane);
            uint64_t t1 = __shfl((unsigned long long)k1, lane & 15, 64);
            uint64_t km = (lane < 16) ? k0 : ((lane < 32) ? t1 : ~0ull);
            mykey = sort64(km, lane);
        }
        uint32_t mhi   = (uint32_t)(mykey >> 32);
        uint32_t rbits = (mhi & 0x80000000u) ? (mhi ^ 0x80000000u) : ~mhi;
        float    d2w   = __uint_as_float(rbits);
        myidxA[j] = (int)(uint32_t)(mykey & 0xFFFFFFFFull);
        float recip = (lane < KQ) ? (1.0f / (d2w + 1e-8f)) : 0.0f;
        float tot = recip;
        #pragma unroll
        for (int sh = 1; sh < 16; sh <<= 1) tot += __shfl_xor(tot, sh, 64);
        mywgtA[j] = recip / tot;                   // valid in lanes 0..15
    }

    // NO BARRIER: wball -> cat overwrite is wave-local (private region).

    // ------- Stage 2: build cat (bf16 hi/lo split) in own region -------
    ushort* ch = (ushort*)myreg;                   // [4][392] hi
    ushort* cl = (ushort*)(myreg + 3136);          // [4][392] lo
    const float* p2b = points2 + (size_t)b * NQ * D2Q;
    #pragma unroll
    for (int j = 0; j < 4; ++j) {
        // p1 part: 128 floats, lanes 0..31 (orig query row via permutation)
        if (lane < 32) {
            float4 p = ((const float4*)(points1 +
                        (size_t)(b * NQ + oqi[j]) * D1Q))[lane];
            ushort4 hv, lv;
            hv.x = f2bf(p.x); lv.x = f2bf(p.x - bf2f(hv.x));
            hv.y = f2bf(p.y); lv.y = f2bf(p.y - bf2f(hv.y));
            hv.z = f2bf(p.z); lv.z = f2bf(p.z - bf2f(hv.z));
            hv.w = f2bf(p.w); lv.w = f2bf(p.w - bf2f(hv.w));
            *(ushort4*)&ch[j * 392 + lane * 4] = hv;
            *(ushort4*)&cl[j * 392 + lane * 4] = lv;
        }
        // interp part: 256 floats, all 64 lanes; k ascending (reference order)
        float4 acc = make_float4(0.f, 0.f, 0.f, 0.f);
        #pragma unroll
        for (int k = 0; k < KQ; ++k) {
            int   kk = __builtin_amdgcn_readlane(myidxA[j], k);
            float wk = __uint_as_float((uint32_t)__builtin_amdgcn_readlane(
                           (int)__float_as_uint(mywgtA[j]), k));
            float4 row = ((const float4*)(p2b + (size_t)kk * D2Q))[lane];
            acc.x = fmaf(wk, row.x, acc.x);
            acc.y = fmaf(wk, row.y, acc.y);
            acc.z = fmaf(wk, row.z, acc.z);
            acc.w = fmaf(wk, row.w, acc.w);
        }
        {
            ushort4 hv, lv;
            hv.x = f2bf(acc.x); lv.x = f2bf(acc.x - bf2f(hv.x));
            hv.y = f2bf(acc.y); lv.y = f2bf(acc.y - bf2f(hv.y));
            hv.z = f2bf(acc.z); lv.z = f2bf(acc.z - bf2f(hv.z));
            hv.w = f2bf(acc.w); lv.w = f2bf(acc.w - bf2f(hv.w));
            *(ushort4*)&ch[j * 392 + D1Q + lane * 4] = hv;
            *(ushort4*)&cl[j * 392 + D1Q + lane * 4] = lv;
        }
    }
    __syncthreads();   // the ONE barrier: GEMM reads all waves' cat regions

    // ------- Stage 3: MFMA GEMM  C[16][128] = cat[16][384] @ Wt[384][128] -------
    {
        const int arow = lane & 15;
        const int koff = (lane >> 4) * 8;
        const int ct0  = w * 2;
        // row arow lives in region (arow>>2) at sub-row (arow&3)
        const char* rowb = smem + (arow >> 2) * WREG + (arow & 3) * 784;
        f32x4v acc0 = {0.f, 0.f, 0.f, 0.f};
        f32x4v acc1 = {0.f, 0.f, 0.f, 0.f};
        #pragma unroll 4
        for (int kt = 0; kt < 12; ++kt) {
            short8v ah = *(const short8v*)(rowb + (kt * 32 + koff) * 2);
            short8v al = *(const short8v*)(rowb + 3136 + (kt * 32 + koff) * 2);
            const ushort* bhp = Wfh + ((size_t)(kt * 8 + ct0) * 64 + lane) * 8;
            const ushort* blp = Wfl + ((size_t)(kt * 8 + ct0) * 64 + lane) * 8;
            short8v bh0 = *(const short8v*)bhp;
            short8v bl0 = *(const short8v*)blp;
            short8v bh1 = *(const short8v*)(bhp + 512);
            short8v bl1 = *(const short8v*)(blp + 512);
            acc0 = __builtin_amdgcn_mfma_f32_16x16x32_bf16(ah, bh0, acc0, 0, 0, 0);
            acc0 = __builtin_amdgcn_mfma_f32_16x16x32_bf16(al, bh0, acc0, 0, 0, 0);
            acc0 = __builtin_amdgcn_mfma_f32_16x16x32_bf16(ah, bl0, acc0, 0, 0, 0);
            acc1 = __builtin_amdgcn_mfma_f32_16x16x32_bf16(ah, bh1, acc1, 0, 0, 0);
            acc1 = __builtin_amdgcn_mfma_f32_16x16x32_bf16(al, bh1, acc1, 0, 0, 0);
            acc1 = __builtin_amdgcn_mfma_f32_16x16x32_bf16(ah, bl1, acc1, 0, 0, 0);
        }
        // C/D layout: col = lane&15, row = (lane>>4)*4 + r (m89-verified);
        // rows scatter through the query permutation.
        const int col0   = ct0 * 16 + (lane & 15);
        const int r0slot = (lane >> 4) * 4;
        const float bv0 = bias[col0];
        const float bv1 = bias[col0 + 16];
        #pragma unroll
        for (int r = 0; r < 4; ++r) {
            int oq = (int)qsl[r0slot + r];
            size_t rowoff = (size_t)(b * NQ + oq) * OUTQ;
            out[rowoff + col0]      = acc0[r] + bv0;
            out[rowoff + col0 + 16] = acc1[r] + bv1;
        }
    }
}

// ---------------------------------------------------------------------------
// Launch
// ---------------------------------------------------------------------------
extern "C" void kernel_launch(void* const* d_in, const int* in_sizes, int n_in,
                              void* d_out, int out_size, void* d_ws, size_t ws_size,
                              hipStream_t stream) {
    const float* xyz1    = (const float*)d_in[0];
    const float* xyz2    = (const float*)d_in[1];
    const float* points1 = (const float*)d_in[2];
    const float* points2 = (const float*)d_in[3];
    const float* W       = (const float*)d_in[4];
    const float* bias    = (const float*)d_in[5];

    char* ws = (char*)d_ws;
    ushort*   Wfh     = (ushort*)(ws + WS_WFH);
    ushort*   Wfl     = (ushort*)(ws + WS_WFL);
    float4*   sp_xyzn = (float4*)(ws + WS_SPXYZ);
    float4*   qs_xyzw = (float4*)(ws + WS_QSXYZ);
    ushort*   sp_idx  = (ushort*)(ws + WS_SPIDX);
    ushort*   qs_idx  = (ushort*)(ws + WS_QSIDX);
    float4*   gblo    = (float4*)(ws + WS_GBLO);
    float4*   gbhi    = (float4*)(ws + WS_GBHI);

    prep_all_kernel<<<52, 1024, 0, stream>>>(W, Wfh, Wfl, xyz1, xyz2,
                                             sp_xyzn, qs_xyzw, sp_idx, qs_idx,
                                             gblo, gbhi);
    fused_kernel<<<(BQ * NQ) / 16, 256, 0, stream>>>(
        sp_xyzn, sp_idx, qs_xyzw, qs_idx, points1, points2,
        Wfh, Wfl, bias, gblo, gbhi, (float*)d_out);
}